// Round 5
// baseline (197.629 us; speedup 1.0000x reference)
//
#include <hip/hip_runtime.h>

#define BB 8
#define NN 8192
#define SS 2048
#define CC 64
#define NS 32
#define COUT 67   // 3 xyz + 64 feature channels
#define QT 8      // queries per gather block
#define PMAX 35   // planes in half 0 (3 xyz + 32 feat); half 1 has 32

// ---------------- Kernel 0: xyz -> SoA transpose (tiny) ----------------
__global__ __launch_bounds__(256) void transpose_kernel(
    const float* __restrict__ xyz,   // (B, N, 3)
    float* __restrict__ xs, float* __restrict__ ys, float* __restrict__ zs)
{
    const int t = blockIdx.x * 256 + threadIdx.x;   // 0 .. B*N-1
    const float* p = xyz + (size_t)t * 3;
    xs[t] = p[0];
    ys[t] = p[1];
    zs[t] = p[2];
}

// ---------------- Kernel A: ball-query scan, 2 points/lane, SoA ----------
// 512 points per latency chain (12 independent float2 loads), 4 ballot
// groups of 128 points. Packed-f32-eligible math; exact rounding order
// ((dx*dx + dy*dy) + dz*dz) preserved per component, fma contraction off.
__global__ __launch_bounds__(256) void scan_kernel(
    const float* __restrict__ xs,
    const float* __restrict__ ys,
    const float* __restrict__ zs,
    const float* __restrict__ new_xyz,  // (B, S, 3)
    int* __restrict__ idx_ws)           // (B*S, NS)
{
#pragma clang fp contract(off)
    const int wave = threadIdx.x >> 6;
    const int lane = threadIdx.x & 63;
    const int qid  = blockIdx.x * 4 + wave;
    const int b = qid >> 11;
    const int s = qid & 2047;

    const float R2 = 0.04f;   // f32 nearest of 0.2*0.2; strict '<' matches ref

    const float* ctr = new_xyz + ((size_t)b * SS + s) * 3;
    const float cx = ctr[0], cy = ctr[1], cz = ctr[2];

    const float2* xb = (const float2*)(xs + (size_t)b * NN);
    const float2* yb = (const float2*)(ys + (size_t)b * NN);
    const float2* zb = (const float2*)(zs + (size_t)b * NN);

    int* myidx = idx_ws + (size_t)qid * NS;
    const unsigned long long lt = (1ull << lane) - 1ull;

    int total = 0;
    int firstIdx = -1;
    for (int j0 = 0; j0 < NN && total < NS; j0 += 512) {
        float2 X[4], Y[4], Z[4];
#pragma unroll
        for (int u = 0; u < 4; ++u) {
            const int i2 = (j0 >> 1) + u * 64 + lane;   // float2 index
            X[u] = xb[i2];
            Y[u] = yb[i2];
            Z[u] = zb[i2];
        }
#pragma unroll
        for (int u = 0; u < 4; ++u) {
            const float dx0 = X[u].x - cx, dx1 = X[u].y - cx;
            const float dy0 = Y[u].x - cy, dy1 = Y[u].y - cy;
            const float dz0 = Z[u].x - cz, dz1 = Z[u].y - cz;
            float d20 = dx0 * dx0;
            float d21 = dx1 * dx1;
            d20 = d20 + dy0 * dy0;
            d21 = d21 + dy1 * dy1;
            d20 = d20 + dz0 * dz0;      // ((dx^2+dy^2)+dz^2), no contraction
            d21 = d21 + dz1 * dz1;
            const bool h0 = d20 < R2;
            const bool h1 = d21 < R2;
            const unsigned long long lo = __ballot(h0);
            const unsigned long long hi = __ballot(h1);
            const int jg = j0 + u * 128;
            if (firstIdx < 0 && (lo | hi)) {
                int cand = 0x7fffffff;
                if (lo) cand = jg + 2 * __builtin_ctzll(lo);
                if (hi) {
                    const int c2 = jg + 2 * __builtin_ctzll(hi) + 1;
                    cand = (c2 < cand) ? c2 : cand;
                }
                firstIdx = cand;
            }
            const int clo = __popcll(lo & lt);
            const int chi = __popcll(hi & lt);
            if (h0) {
                const int pos = total + clo + chi;
                if (pos < NS) myidx[pos] = jg + 2 * lane;
            }
            if (h1) {
                const int pos = total + clo + chi + (h0 ? 1 : 0);
                if (pos < NS) myidx[pos] = jg + 2 * lane + 1;
            }
            total += __popcll(lo) + __popcll(hi);
        }
    }
    if (total < NS) {
        const int fill = (total > 0) ? firstIdx : 0;
        if (lane >= total && lane < NS) myidx[lane] = fill;
    }
}

// ---------------- Kernel B: gather, LDS-transposed contiguous writes --------
// (R4 version: measured equal to R2's pattern, kept for its full-line reads
// and 1KB-contiguous writes.)
__global__ __launch_bounds__(256) void gather_kernel(
    const float* __restrict__ xyz,      // (B, N, 3)
    const float* __restrict__ new_xyz,  // (B, S, 3)
    const float* __restrict__ feat,     // (B, N, C)
    const int* __restrict__ idx_ws,     // (B*S, NS)
    float* __restrict__ out)            // (B, 67, S, NS)
{
#pragma clang fp contract(off)
    __shared__ float tile[PMAX * QT * NS];  // 35 KB
    __shared__ int idx_sh[QT * NS];         // 1 KB

    const int t     = threadIdx.x;          // = q*32 + k
    const int sTile = blockIdx.x;           // 0..255
    const int half  = blockIdx.y;           // 0..1
    const int b     = blockIdx.z;           // 0..7

    const int s0 = sTile * QT;
    const int qbase = (b << 11) + s0;

    idx_sh[t] = idx_ws[(size_t)qbase * NS + t];
    __syncthreads();

    const int q = t >> 5;
    const int row = idx_sh[t];

    const float* frow = feat + ((size_t)b * NN + row) * CC + half * 32;
    if (half == 0) {
        const float* ctr = new_xyz + ((size_t)b * SS + s0 + q) * 3;
        const float* p   = xyz + ((size_t)b * NN + row) * 3;
        tile[0 * 256 + t] = p[0] - ctr[0];
        tile[1 * 256 + t] = p[1] - ctr[1];
        tile[2 * 256 + t] = p[2] - ctr[2];
#pragma unroll
        for (int i = 0; i < 8; ++i) {
            const float4 f = *(const float4*)(frow + i * 4);
            tile[(3 + i * 4 + 0) * 256 + t] = f.x;
            tile[(3 + i * 4 + 1) * 256 + t] = f.y;
            tile[(3 + i * 4 + 2) * 256 + t] = f.z;
            tile[(3 + i * 4 + 3) * 256 + t] = f.w;
        }
    } else {
#pragma unroll
        for (int i = 0; i < 8; ++i) {
            const float4 f = *(const float4*)(frow + i * 4);
            tile[(i * 4 + 0) * 256 + t] = f.x;
            tile[(i * 4 + 1) * 256 + t] = f.y;
            tile[(i * 4 + 2) * 256 + t] = f.z;
            tile[(i * 4 + 3) * 256 + t] = f.w;
        }
    }
    __syncthreads();

    const int P     = half ? 32 : PMAX;
    const int cbase = half ? PMAX : 0;
    const int wv = t >> 6;
    const int ln = t & 63;
    const size_t plane = (size_t)SS * NS;
    float* ob = out + (((size_t)b * COUT + cbase) * SS + s0) * NS;
#pragma unroll
    for (int i = 0; i < 9; ++i) {
        const int p = i * 4 + wv;
        if (p < P) {
            const float4 v = *(const float4*)(tile + p * 256 + ln * 4);
            *(float4*)(ob + (size_t)p * plane + ln * 4) = v;
        }
    }
}

extern "C" void kernel_launch(void* const* d_in, const int* in_sizes, int n_in,
                              void* d_out, int out_size, void* d_ws, size_t ws_size,
                              hipStream_t stream) {
    const float* xyz     = (const float*)d_in[0];
    const float* new_xyz = (const float*)d_in[1];
    const float* feat    = (const float*)d_in[2];
    float* out = (float*)d_out;

    int*   idx_ws = (int*)d_ws;                        // 2 MB
    float* xs = (float*)((char*)d_ws + (size_t)BB * SS * NS * 4);
    float* ys = xs + (size_t)BB * NN;                  // 3 x 256 KB SoA
    float* zs = ys + (size_t)BB * NN;

    transpose_kernel<<<dim3(BB * NN / 256), dim3(256), 0, stream>>>(xyz, xs, ys, zs);
    scan_kernel<<<dim3((BB * SS) / 4), dim3(256), 0, stream>>>(xs, ys, zs, new_xyz, idx_ws);
    gather_kernel<<<dim3(SS / QT, 2, BB), dim3(256), 0, stream>>>(xyz, new_xyz, feat, idx_ws, out);
}